// Round 10
// baseline (346.108 us; speedup 1.0000x reference)
//
#include <hip/hip_runtime.h>

// ---------------------------------------------------------------------------
// Fused QKV-projection + attention (B=8, C=2048, N=512), fp32 in/out.
// Precision: fp32 -> fp16 hi/lo split. Projections: full 3-term fp16 MFMA.
// Attention logits: 1.5-term (S = qh*kh). Measured absmax 1.71e-3 vs 4.57e-3.
// Round 10: SINGLE COUNTED-VMCNT BARRIER PER TILE (T4). R9 still had 2
// workgroup barriers/tile (LIGHT_BARRIER + syncthreads w/ vmcnt(0) drain) =
// lockstep x128. Now per tile: STAGE -> V prefetch (16 volatile-asm loads,
// countable) -> QK -> own-half softmax/P-store -> ONE barrier
// {vmcnt(16)=stage-done, lgkmcnt(0)=P visible} -> rescale -> vmcnt(0)+
// sched_barrier (V ready; rule #18) -> PV. plds/tmx double-buffered (t&1) so
// the end-of-tile syncthreads is gone; waves drift <=1 tile. s_setprio(1)
// around MFMA clusters (T5).
// ---------------------------------------------------------------------------

typedef _Float16 half_t;
typedef __attribute__((ext_vector_type(8))) _Float16 half8;
typedef __attribute__((ext_vector_type(4))) _Float16 half4;
typedef __attribute__((ext_vector_type(4))) float    f32x4;

#define MFMA16x32(A_, B_, C_) __builtin_amdgcn_mfma_f32_16x16x32_f16((A_), (B_), (C_), 0, 0, 0)

// the ONE per-tile barrier: waits K-stage (4 oldest vmem) + LDS ops; V floats.
#define STAGE_BARRIER() asm volatile("s_waitcnt vmcnt(16) lgkmcnt(0)\n\ts_barrier" ::: "memory")
// V-ready wait; sched_barrier stops register-only MFMAs hoisting above (rule 18)
#define WAIT_ALL_VMEM() do { asm volatile("s_waitcnt vmcnt(0)" ::: "memory"); \
                             __builtin_amdgcn_sched_barrier(0); } while (0)

__device__ __forceinline__ void gload_lds16(const void* g, void* l) {
  __builtin_amdgcn_global_load_lds(
      (const __attribute__((address_space(1))) void*)g,
      (__attribute__((address_space(3))) void*)l, 16, 0, 0);
}

// max-reduce over each 16-lane row via DPP (quad_perm xor1/xor2, row_ror 4/8).
__device__ __forceinline__ float dpp_max16(float x) {
  int t;
  t = __builtin_amdgcn_update_dpp(__float_as_int(x), __float_as_int(x), 0xB1, 0xF, 0xF, false);
  x = fmaxf(x, __int_as_float(t));
  t = __builtin_amdgcn_update_dpp(__float_as_int(x), __float_as_int(x), 0x4E, 0xF, 0xF, false);
  x = fmaxf(x, __int_as_float(t));
  t = __builtin_amdgcn_update_dpp(__float_as_int(x), __float_as_int(x), 0x124, 0xF, 0xF, false);
  x = fmaxf(x, __int_as_float(t));
  t = __builtin_amdgcn_update_dpp(__float_as_int(x), __float_as_int(x), 0x128, 0xF, 0xF, false);
  x = fmaxf(x, __int_as_float(t));
  return x;
}

// ---- split fp32 [rows][cols] -> fp16 [rows][2*cols] = [hi | lo] -------------
__global__ void split_hilo(const float* __restrict__ src, half_t* __restrict__ dst,
                           int rows, int cols) {
  int idx = blockIdx.x * 256 + threadIdx.x;
  int total = rows * cols / 4;
  if (idx >= total) return;
  f32x4 v = ((const f32x4*)src)[idx];
  int e = idx * 4;
  int r = e / cols, c = e % cols;
  half4 h, l;
#pragma unroll
  for (int j = 0; j < 4; ++j) {
    float f = v[j];
    _Float16 hh = (_Float16)f;
    h[j] = hh;
    l[j] = (_Float16)(f - (float)hh);
  }
  *(half4*)&dst[(size_t)r * (2 * cols) + c] = h;
  *(half4*)&dst[(size_t)r * (2 * cols) + c + cols] = l;
}

// ---- projection GEMM (unchanged from R9) -------------------------------------
// MODE 2: out[t*512 + m] = f16(val)                       (q/k, hi-only compact)
// MODE 1: out[(t>>5)*16384 + m*32 + (t&31)] = f16(val)    (v kv-blocked)
template <int MODE>
__global__ __launch_bounds__(256) void proj_gemm(
    const half_t* __restrict__ A, const half_t* __restrict__ Bm,
    const float* __restrict__ bias, half_t* __restrict__ out) {
  __shared__ half_t At[128 * 64];
  __shared__ half_t Bt[128 * 64];
  const int tid = threadIdx.x;
  const int lane = tid & 63, wv = tid >> 6;
  const int g = lane >> 4, li = lane & 15;
  const int wm = wv >> 1, wn = wv & 1;
  const int M0 = blockIdx.x * 128, N0 = blockIdx.y * 128;

  const f32x4 kZero = {0.f, 0.f, 0.f, 0.f};
  f32x4 acc[4][4];
#pragma unroll
  for (int i = 0; i < 4; ++i)
#pragma unroll
    for (int j = 0; j < 4; ++j) acc[i][j] = kZero;

  for (int kt = 0; kt < 24; ++kt) {
    const int kc = kt * 64;
    const int ab = kc & 1023;
    const int bb = (kc < 512) ? kc : (kc - 512);
    __syncthreads();
#pragma unroll
    for (int s2 = 0; s2 < 4; ++s2) {
      int bid = tid + 256 * s2;
      int row = bid >> 3, blk = bid & 7;
      half8 va = *(const half8*)&A[(size_t)(M0 + row) * 1024 + ab + blk * 8];
      *(half8*)&At[row * 64 + ((blk ^ (row & 7)) * 8)] = va;
      half8 vb = *(const half8*)&Bm[(size_t)(N0 + row) * 1024 + bb + blk * 8];
      *(half8*)&Bt[row * 64 + ((blk ^ (row & 7)) * 8)] = vb;
    }
    __syncthreads();
#pragma unroll
    for (int kk = 0; kk < 2; ++kk) {
      half8 af[4], bf[4];
#pragma unroll
      for (int i = 0; i < 4; ++i) {
        int ar = wm * 64 + i * 16 + li;
        af[i] = *(const half8*)&At[ar * 64 + (((4 * kk + g) ^ (ar & 7)) * 8)];
        int br = wn * 64 + i * 16 + li;
        bf[i] = *(const half8*)&Bt[br * 64 + (((4 * kk + g) ^ (br & 7)) * 8)];
      }
#pragma unroll
      for (int i = 0; i < 4; ++i)
#pragma unroll
        for (int j = 0; j < 4; ++j) acc[i][j] = MFMA16x32(af[i], bf[j], acc[i][j]);
    }
  }

  if (MODE == 2) {
#pragma unroll
    for (int i = 0; i < 4; ++i) {
      int trow = M0 + wm * 64 + i * 16 + 4 * g;
#pragma unroll
      for (int j = 0; j < 4; ++j) {
        int m = N0 + wn * 64 + j * 16 + li;
        float bs = bias[m];
#pragma unroll
        for (int r = 0; r < 4; ++r) {
          out[(size_t)(trow + r) * 512 + m] = (_Float16)(acc[i][j][r] + bs);
        }
      }
    }
  } else {
#pragma unroll
    for (int i = 0; i < 4; ++i) {
      int m0r = M0 + wm * 64 + i * 16 + 4 * g;
#pragma unroll
      for (int r = 0; r < 4; ++r) {
        int m = m0r + r;
        float bs = bias[m];
#pragma unroll
        for (int j = 0; j < 4; ++j) {
          int tt = N0 + wn * 64 + j * 16 + li;
          out[(size_t)(tt >> 5) * 16384 + (size_t)m * 32 + (tt & 31)] =
              (_Float16)(acc[i][j][r] + bs);
        }
      }
    }
  }
}

// ---- flash attention v10 ----------------------------------------------------
// grid 256 (1 block/CU), 512 threads = 8 waves = 4 pair-groups x 16 q-rows.
// Wave pair: wbit splits kv (QK) and n (PV). K-hi tile double-buffered via
// global_load_lds; V prefetched into regs via volatile asm (countable vmcnt).
// ONE barrier per tile (vmcnt(16)+lgkmcnt(0)); plds/tmx double-buffered.
__global__ __attribute__((amdgpu_flat_work_group_size(512, 512),
                          amdgpu_waves_per_eu(2, 2))) void flash_attn(
    const half_t* __restrict__ qs, const half_t* __restrict__ ks,
    const half_t* __restrict__ vblk, float* __restrict__ outp) {
  __shared__ half_t kt[2][20480];         // 2 x 40 KB declared (32 KB used each)
  __shared__ half_t plds[2][4][16][40];   // P, double-buffered by t&1
  __shared__ float  tmx[2][4][2][16];     // half row-max, double-buffered
  __shared__ float  lx[4][16];            // final l exchange [grp][row]

  const int blk0 = blockIdx.x;
  const int logical = (blk0 & 7) * 32 + (blk0 >> 3);   // XCD-chunked (256%8==0)
  const int b  = logical >> 5;                         // batch = XCD
  const int c0 = (logical & 31) * 64;
  const int tid = threadIdx.x;
  const int wv = tid >> 6, lane = tid & 63;
  const int grp = wv >> 1, wbit = wv & 1;
  const int g = lane >> 4, li = lane & 15;
  const int qr0 = c0 + grp * 16;
  const int nh0 = wbit * 256;          // this wave's n-half for PV/output

  const char* kbytes = (const char*)(ks + (size_t)b * 2048 * 512);

  // Q-hi fragments pinned in registers (volatile asm: loaded exactly once):
  const half_t* qrow = qs + (size_t)(b * 2048 + qr0 + li) * 512 + 8 * g;
  half8 qh[16];
#pragma unroll
  for (int c = 0; c < 16; ++c) {
    const half_t* ah = qrow + c * 32;
    asm volatile("global_load_dwordx4 %0, %1, off" : "=v"(qh[c]) : "v"(ah));
  }
  asm volatile("s_waitcnt vmcnt(0)" ::: "memory");

  const f32x4 kZero = {0.f, 0.f, 0.f, 0.f};
  f32x4 o[16];
#pragma unroll
  for (int i = 0; i < 16; ++i) o[i] = kZero;
  float mr[4] = {-3e38f, -3e38f, -3e38f, -3e38f};  // joint running max, rows 4g+r
  float m_li = -3e38f, l_li = 0.f;                 // joint running max/l, row li

  // stage K-hi tile: 32 rows x 1024 B (contiguous) = 2048 16B-segs, 4/thread.
  auto STAGE = [&](int kv0s, int bufs) {
#pragma unroll
    for (int i2 = 0; i2 < 4; ++i2) {
      int seg = i2 * 512 + tid;
      int r = seg >> 6, bb = seg & 63;
      int bsrc = bb ^ (r & 7);
      gload_lds16(kbytes + (size_t)(kv0s + r) * 1024 + bsrc * 16,
                  (void*)&kt[bufs][seg * 8]);
    }
  };

  STAGE(0, 0);
  asm volatile("s_waitcnt vmcnt(0)\n\ts_barrier" ::: "memory");
  int cur = 0;

#pragma unroll 1
  for (int t = 0; t < 64; ++t) {
    const int pb = t & 1;

    // ---- issue next K stage FIRST (oldest 4 vmem ops -> vmcnt(16) at barrier)
    if (t + 1 < 64) STAGE((t + 1) * 32, cur ^ 1);

    // ---- V prefetch for THIS tile: 16 volatile-asm loads (countable) ----
    const half_t* vtile = vblk + ((size_t)(b * 64 + t)) * 16384 +
                          (size_t)nh0 * 32 + li * 32 + 8 * g;
    half8 vreg[16];
#pragma unroll
    for (int ns4 = 0; ns4 < 4; ++ns4) {
      const half_t* vb4 = vtile + ns4 * 2048;   // 4096 B steps
      asm volatile("global_load_dwordx4 %0, %1, off"             : "=v"(vreg[4 * ns4 + 0]) : "v"(vb4));
      asm volatile("global_load_dwordx4 %0, %1, off offset:1024" : "=v"(vreg[4 * ns4 + 1]) : "v"(vb4));
      asm volatile("global_load_dwordx4 %0, %1, off offset:2048" : "=v"(vreg[4 * ns4 + 2]) : "v"(vb4));
      asm volatile("global_load_dwordx4 %0, %1, off offset:3072" : "=v"(vreg[4 * ns4 + 3]) : "v"(vb4));
    }

    // ---- QK: S[16q][16kv(this wave)] = qh . kh^T, 2 MFMA chains ----
    const half_t* krow = &kt[cur][(wbit * 16 + li) * 512];
    const int swz = li & 7;
    f32x4 sA = kZero, sB = kZero;
    __builtin_amdgcn_s_setprio(1);
#pragma unroll
    for (int c = 0; c < 16; c += 2) {
      half8 k0 = *(const half8*)&krow[((4 * c + g) ^ swz) * 8];
      half8 k1 = *(const half8*)&krow[((4 * c + 4 + g) ^ swz) * 8];
      sA = MFMA16x32(qh[c], k0, sA);
      sB = MFMA16x32(qh[c + 1], k1, sB);
    }
    __builtin_amdgcn_s_setprio(0);
    f32x4 sv = sA + sB;

    // ---- per-row max of THIS half (DPP, pure VALU); P normalized by it ----
    float tm[4];
#pragma unroll
    for (int r = 0; r < 4; ++r) tm[r] = dpp_max16(sv[r]);
#pragma unroll
    for (int r = 0; r < 4; ++r) {
      float p = __expf(sv[r] - tm[r]);            // <= 1
      plds[pb][grp][4 * g + r][li + 16 * wbit] = (half_t)p;
    }
    if (li == 0) {
#pragma unroll
      for (int r = 0; r < 4; ++r) tmx[pb][grp][wbit][4 * g + r] = tm[r];
    }

    STAGE_BARRIER();   // THE barrier: stage done (vmcnt16) + P visible (lgkm0)

    // ---- joint max, defer-max (THR=8), pa rescale ----
    f32x4 t0 = *(const f32x4*)&tmx[pb][grp][0][4 * g];
    f32x4 t1 = *(const f32x4*)&tmx[pb][grp][1][4 * g];
    float tA = tmx[pb][grp][0][li], tB = tmx[pb][grp][1][li];
    float tf[4];
#pragma unroll
    for (int r = 0; r < 4; ++r) tf[r] = fmaxf(t0[r], t1[r]);
    int grow = (tf[0] > mr[0] + 8.f) | (tf[1] > mr[1] + 8.f) |
               (tf[2] > mr[2] + 8.f) | (tf[3] > mr[3] + 8.f);
    if (__any(grow)) {
      float al[4];
#pragma unroll
      for (int r = 0; r < 4; ++r) {
        float mn = fmaxf(mr[r], tf[r]);
        al[r] = __expf(mr[r] - mn);
        mr[r] = mn;
      }
      f32x4 av = {al[0], al[1], al[2], al[3]};
#pragma unroll
      for (int i = 0; i < 16; ++i) o[i] *= av;
      float mnli = fmaxf(m_li, fmaxf(tA, tB));
      l_li *= __expf(m_li - mnli);
      m_li = mnli;
    }
    // scale for this lane's pa fragment (cols 8g..8g+7 live in half g>>1):
    float sh = __expf(((g < 2) ? tA : tB) - m_li);   // <= e^8 (defer bound)
    half_t sh16 = (half_t)sh;
    half8 pa = *(const half8*)&plds[pb][grp][li][8 * g];
#pragma unroll
    for (int e = 0; e < 8; ++e) pa[e] = pa[e] * sh16;

    // l harvested from the scaled pa fragment
    float lp = 0.f;
#pragma unroll
    for (int e = 0; e < 8; ++e) lp += (float)pa[e];
    lp += __shfl_xor(lp, 16);
    lp += __shfl_xor(lp, 32);
    l_li += lp;

    WAIT_ALL_VMEM();   // V regs valid (also covers stage, already done)

    // ---- PV from prefetched V registers ----
    __builtin_amdgcn_s_setprio(1);
#pragma unroll
    for (int ns = 0; ns < 16; ++ns) {
      o[ns] = MFMA16x32(pa, vreg[ns], o[ns]);
    }
    __builtin_amdgcn_s_setprio(0);

    cur ^= 1;          // no end-of-tile barrier: plds/tmx double-buffered,
                       // kt overwrite-after-barrier argument in header comment
  }

  // ---- final normalization: l in li-layout, o rows are 4g+r ----
  if (wbit == 0 && g == 0) lx[grp][li] = l_li;
  __syncthreads();
  float inv[4];
#pragma unroll
  for (int r = 0; r < 4; ++r) inv[r] = 1.0f / (lx[grp][4 * g + r] * 22.62741699796952f);

  float* ob = outp + (size_t)b * 1048576 + qr0 + 4 * g;
#pragma unroll
  for (int ns = 0; ns < 16; ++ns) {
#pragma unroll
    for (int r = 0; r < 4; ++r) {
      ob[(size_t)(nh0 + ns * 16 + li) * 2048 + r] = o[ns][r] * inv[r];
    }
  }
}

// ---------------------------------------------------------------------------
extern "C" void kernel_launch(void* const* d_in, const int* in_sizes, int n_in,
                              void* d_out, int out_size, void* d_ws, size_t ws_size,
                              hipStream_t stream) {
  const float* x  = (const float*)d_in[0];
  const float* Wq = (const float*)d_in[1];
  const float* bq = (const float*)d_in[2];
  const float* Wk = (const float*)d_in[3];
  const float* bk = (const float*)d_in[4];
  const float* Wv = (const float*)d_in[5];
  const float* bv = (const float*)d_in[6];

  half_t* xs  = (half_t*)d_ws;                  // [16384][1024] hi|lo
  half_t* qsb = xs  + (size_t)16384 * 1024;     // [16384][512]  hi only
  half_t* ksb = qsb + (size_t)16384 * 512;      // [16384][512]  hi only
  half_t* vtb = ksb + (size_t)16384 * 512;      // [512 blk][512 n][32 kv]
  half_t* wqs = vtb + (size_t)512 * 16384;      // [512][1024]
  half_t* wks = wqs + (size_t)512 * 1024;
  half_t* wvs = wks + (size_t)512 * 1024;

  split_hilo<<<dim3(16384 * 512 / 4 / 256), 256, 0, stream>>>(x, xs, 16384, 512);
  split_hilo<<<dim3(512 * 512 / 4 / 256), 256, 0, stream>>>(Wq, wqs, 512, 512);
  split_hilo<<<dim3(512 * 512 / 4 / 256), 256, 0, stream>>>(Wk, wks, 512, 512);
  split_hilo<<<dim3(512 * 512 / 4 / 256), 256, 0, stream>>>(Wv, wvs, 512, 512);

  proj_gemm<2><<<dim3(128, 4), 256, 0, stream>>>(xs, wqs, bq, qsb);
  proj_gemm<2><<<dim3(128, 4), 256, 0, stream>>>(xs, wks, bk, ksb);
  proj_gemm<1><<<dim3(4, 128), 256, 0, stream>>>(wvs, xs, bv, vtb);

  flash_attn<<<dim3(256), 512, 0, stream>>>(qsb, ksb, vtb, (float*)d_out);
}